// Round 3
// baseline (8356.322 us; speedup 1.0000x reference)
//
#include <hip/hip_runtime.h>
#include <math.h>
#include <stdint.h>

#define TOKENS 32768
#define DM 2048
#define DH 1024
#define NE 16
#define BM 128
#define BN 512
#define NPASS 2
#define NSTAGE 64          // DM / 32
#define TAU 1e-3f

// output layout (floats): gates[T*2] | indices[T*2] | probs[T*16]
#define OFF_IDX  (TOKENS * 2)
#define OFF_PROB (TOKENS * 4)

// ws layout (bytes): [0] count (int), [1024] list (32768 int)  -> 132 KB total
#define WS_LIST 1024

typedef short  bf16x8 __attribute__((ext_vector_type(8)));
typedef float  f32x16 __attribute__((ext_vector_type(16)));

// truncation split: hi = top-16-bit bf16 of f; lo = top-16-bit bf16 of (f - hi).
// pack two adjacent elements' bf16 into one dword (little-endian order).

// ---------------- fused GEMM1(MFMA bf16-split, on-the-fly W1) + GEMM2 + softmax + top2 + flag ----------------
__global__ __launch_bounds__(512, 2)
void router_mfma(const float* __restrict__ x, const float* __restrict__ W1,
                 const float* __restrict__ b1, const float* __restrict__ W2,
                 const float* __restrict__ b2, float* __restrict__ out,
                 int* __restrict__ cnt, int* __restrict__ list)
{
    __shared__ short xs[BM * 64];        // 16 KB: A tile [128 m][8 slots x 8 shorts], XOR-swizzled
    __shared__ short bs[BN * 64];        // 64 KB: B tile [512 n][8 slots x 8 shorts], XOR-swizzled
    __shared__ float w2t[NE * 128];      // 8 KB
    __shared__ float ls[BM * 17];        // padded logits

    float* h_lds = (float*)bs;           // [128][128], reused
    float* lsred = (float*)bs;           // [2048][4], reused

    const int tid  = threadIdx.x;
    const int wid  = tid >> 6;
    const int lane = tid & 63;
    const int l31  = lane & 31;
    const int lh   = lane >> 5;
    const int sg   = lane & 7;           // row&7 for all frag rows (row ≡ l31 mod 8)
    const int wm   = wid >> 2;           // 0..1
    const int wn   = wid & 3;            // 0..3
    const int m0   = blockIdx.x * BM;

    const int tq  = tid & 31;
    const int egq = (tid >> 5) & 3;
    const int ns  = tid >> 7;

    float lacc[4][4];
    #pragma unroll
    for (int i = 0; i < 4; ++i)
        #pragma unroll
        for (int e = 0; e < 4; ++e) lacc[i][e] = 0.f;

    const int arow = tid >> 2, kq = tid & 3;     // A staging assignment
    const int asig = arow & 7;
    const int nloc = (wid << 6) + lane;          // B staging row 0..511
    const int sgl  = lane & 7;

    for (int p = 0; p < NPASS; ++p) {
        f32x16 acc[2][4];
        #pragma unroll
        for (int mf = 0; mf < 2; ++mf)
            #pragma unroll
            for (int nf = 0; nf < 4; ++nf)
                #pragma unroll
                for (int q = 0; q < 16; ++q) acc[mf][nf][q] = 0.f;

        for (int s = 0; s < NSTAGE; ++s) {
            __syncthreads();   // xs/bs free: previous compute done
            // ---- B stage: W1 [32k x 512n] fp32 -> bf16 hi/lo splits, on the fly ----
            {
                const float* wp = W1 + (size_t)(s * 32) * DH + p * BN + nloc;
                short* rb = bs + nloc * 64;
                #pragma unroll
                for (int h = 0; h < 2; ++h) {
                    float f[16];
                    #pragma unroll
                    for (int j = 0; j < 16; ++j)
                        f[j] = wp[(size_t)(h * 16 + j) * DH];
                    uint32_t hd[8], ld_[8];
                    #pragma unroll
                    for (int q = 0; q < 8; ++q) {
                        uint32_t u0 = __float_as_uint(f[2 * q]);
                        uint32_t u1 = __float_as_uint(f[2 * q + 1]);
                        hd[q] = (u0 >> 16) | (u1 & 0xFFFF0000u);
                        float r0 = f[2 * q]     - __uint_as_float(u0 & 0xFFFF0000u);
                        float r1 = f[2 * q + 1] - __uint_as_float(u1 & 0xFFFF0000u);
                        ld_[q] = (__float_as_uint(r0) >> 16) | (__float_as_uint(r1) & 0xFFFF0000u);
                    }
                    *(int4*)(rb + (((2 * h + 0) ^ sgl) << 3)) =
                        make_int4(hd[0], hd[1], hd[2], hd[3]);
                    *(int4*)(rb + (((2 * h + 1) ^ sgl) << 3)) =
                        make_int4(hd[4], hd[5], hd[6], hd[7]);
                    *(int4*)(rb + (((4 + 2 * h + 0) ^ sgl) << 3)) =
                        make_int4(ld_[0], ld_[1], ld_[2], ld_[3]);
                    *(int4*)(rb + (((4 + 2 * h + 1) ^ sgl) << 3)) =
                        make_int4(ld_[4], ld_[5], ld_[6], ld_[7]);
                }
            }
            // ---- A stage: x fp32 -> bf16 hi/lo splits ----
            {
                const float* xp = x + (size_t)(m0 + arow) * DM + s * 32 + kq * 8;
                float4 v0 = *(const float4*)xp;
                float4 v1 = *(const float4*)(xp + 4);
                float f[8] = {v0.x, v0.y, v0.z, v0.w, v1.x, v1.y, v1.z, v1.w};
                uint32_t hd[4], ld_[4];
                #pragma unroll
                for (int q = 0; q < 4; ++q) {
                    uint32_t u0 = __float_as_uint(f[2 * q]);
                    uint32_t u1 = __float_as_uint(f[2 * q + 1]);
                    hd[q] = (u0 >> 16) | (u1 & 0xFFFF0000u);
                    float r0 = f[2 * q]     - __uint_as_float(u0 & 0xFFFF0000u);
                    float r1 = f[2 * q + 1] - __uint_as_float(u1 & 0xFFFF0000u);
                    ld_[q] = (__float_as_uint(r0) >> 16) | (__float_as_uint(r1) & 0xFFFF0000u);
                }
                short* ra = xs + arow * 64;
                *(int4*)(ra + ((kq ^ asig) << 3))       = make_int4(hd[0], hd[1], hd[2], hd[3]);
                *(int4*)(ra + (((4 + kq) ^ asig) << 3)) = make_int4(ld_[0], ld_[1], ld_[2], ld_[3]);
            }
            __syncthreads();
            // ---- compute: 2 ksteps x {x0w0, x0w1, x1w0} ----
            #pragma unroll
            for (int ks = 0; ks < 2; ++ks) {
                bf16x8 a0[2], a1[2], b0[4], b1f[4];
                #pragma unroll
                for (int mf = 0; mf < 2; ++mf) {
                    int base = (wm * 64 + mf * 32 + l31) * 64;
                    a0[mf] = *(const bf16x8*)(xs + base + (((ks * 2 + lh)) ^ sg) * 8);
                    a1[mf] = *(const bf16x8*)(xs + base + (((4 + ks * 2 + lh)) ^ sg) * 8);
                }
                #pragma unroll
                for (int nf = 0; nf < 4; ++nf) {
                    int base = (wn * 128 + nf * 32 + l31) * 64;
                    b0[nf]  = *(const bf16x8*)(bs + base + (((ks * 2 + lh)) ^ sg) * 8);
                    b1f[nf] = *(const bf16x8*)(bs + base + (((4 + ks * 2 + lh)) ^ sg) * 8);
                }
                #pragma unroll
                for (int mf = 0; mf < 2; ++mf)
                    #pragma unroll
                    for (int nf = 0; nf < 4; ++nf) {
                        acc[mf][nf] = __builtin_amdgcn_mfma_f32_32x32x16_bf16(a0[mf], b0[nf],  acc[mf][nf], 0, 0, 0);
                        acc[mf][nf] = __builtin_amdgcn_mfma_f32_32x32x16_bf16(a0[mf], b1f[nf], acc[mf][nf], 0, 0, 0);
                        acc[mf][nf] = __builtin_amdgcn_mfma_f32_32x32x16_bf16(a1[mf], b0[nf],  acc[mf][nf], 0, 0, 0);
                    }
            }
        }

        // ---- pass epilogue: bias+relu -> h chunks, fused GEMM2 (VALU, exact fp32) ----
        for (int ch = 0; ch < 4; ++ch) {
            __syncthreads();
            if (wn == ch) {
                #pragma unroll
                for (int nf = 0; nf < 4; ++nf) {
                    int col = nf * 32 + l31;
                    float bb = b1[p * BN + ch * 128 + col];
                    #pragma unroll
                    for (int mf = 0; mf < 2; ++mf)
                        #pragma unroll
                        for (int r = 0; r < 16; ++r) {
                            int row = wm * 64 + mf * 32 + (r & 3) + 8 * (r >> 2) + 4 * lh;
                            h_lds[row * 128 + col] = fmaxf(acc[mf][nf][r] + bb, 0.f);
                        }
                }
            }
            #pragma unroll
            for (int q = 0; q < 4; ++q) {
                int i = tid * 4 + q;                        // 0..2047
                int nn = i >> 4, e = i & 15;
                w2t[e * 128 + nn] = W2[(size_t)(p * BN + ch * 128 + nn) * NE + e];
            }
            __syncthreads();
            for (int nn = 0; nn < 32; ++nn) {
                int nL = ns * 32 + ((nn + tq) & 31);        // staggered: conflict-free
                float hv[4], wv[4];
                #pragma unroll
                for (int i = 0; i < 4; ++i) hv[i] = h_lds[(tq * 4 + i) * 128 + nL];
                #pragma unroll
                for (int e = 0; e < 4; ++e) wv[e] = w2t[(egq * 4 + e) * 128 + nL];
                #pragma unroll
                for (int i = 0; i < 4; ++i)
                    #pragma unroll
                    for (int e = 0; e < 4; ++e)
                        lacc[i][e] = fmaf(hv[i], wv[e], lacc[i][e]);
            }
        }
    }

    // ---- reduce partial logits over ns slices ----
    __syncthreads();
    #pragma unroll
    for (int i = 0; i < 4; ++i)
        #pragma unroll
        for (int e = 0; e < 4; ++e)
            lsred[((tq * 4 + i) * 16 + egq * 4 + e) * 4 + ns] = lacc[i][e];
    __syncthreads();
    #pragma unroll
    for (int q = 0; q < 4; ++q) {
        int idx = tid * 4 + q;                              // 0..2047
        int t = idx >> 4, e = idx & 15;
        ls[t * 17 + e] = lsred[idx * 4 + 0] + lsred[idx * 4 + 1] +
                         lsred[idx * 4 + 2] + lsred[idx * 4 + 3] + b2[e];
    }
    __syncthreads();

    // ---- softmax + top2 + flag ----
    if (tid < BM) {
        int t = tid;
        float l[NE]; float mx = -1e30f;
        #pragma unroll
        for (int e = 0; e < NE; ++e) { l[e] = ls[t * 17 + e]; mx = fmaxf(mx, l[e]); }
        float pb[NE]; float ssum = 0.f;
        #pragma unroll
        for (int e = 0; e < NE; ++e) { pb[e] = expf(l[e] - mx); ssum += pb[e]; }
        float inv = 1.f / ssum;
        #pragma unroll
        for (int e = 0; e < NE; ++e) pb[e] *= inv;

        int i1 = 0; float p1 = pb[0];
        #pragma unroll
        for (int e = 1; e < NE; ++e) if (pb[e] > p1) { p1 = pb[e]; i1 = e; }
        int i2 = -1; float p2 = -1.f;
        #pragma unroll
        for (int e = 0; e < NE; ++e) if (e != i1 && pb[e] > p2) { p2 = pb[e]; i2 = e; }
        float p3 = -1.f;
        #pragma unroll
        for (int e = 0; e < NE; ++e) if (e != i1 && e != i2 && pb[e] > p3) p3 = pb[e];

        float denom = p1 + p2 + 1e-8f;
        size_t gt = (size_t)(m0 + t);
        out[gt * 2 + 0] = p1 / denom;
        out[gt * 2 + 1] = p2 / denom;
        out[OFF_IDX + gt * 2 + 0] = (float)i1;
        out[OFF_IDX + gt * 2 + 1] = (float)i2;
        #pragma unroll
        for (int e = 0; e < NE; ++e) out[OFF_PROB + gt * 16 + e] = pb[e];

        if (p1 - p2 < TAU || p2 - p3 < TAU) {
            int k = atomicAdd(cnt, 1);
            list[k] = m0 + t;
        }
    }
}

// ---------------- exact fp32 repair: gathered dense GEMM over flagged tokens ----------------
__global__ __launch_bounds__(256, 2)
void repair_gather(const float* __restrict__ x, const float* __restrict__ W1,
                   const float* __restrict__ b1, const float* __restrict__ W2,
                   const float* __restrict__ b2, float* __restrict__ out,
                   const int* __restrict__ cnt, const int* __restrict__ list)
{
    __shared__ float xsh[64][68];
    __shared__ float wsd[64][64];
    __shared__ float hsh[64][68];
    __shared__ float w2s[64 * NE];
    __shared__ float lsg[64][NE];
    __shared__ int   tokid[64];

    const int tid = threadIdx.x;
    const int tx = tid & 15, ty = tid >> 4;
    const int nrep = cnt[0];

    for (int g = blockIdx.x; g * 64 < nrep; g += gridDim.x) {
        __syncthreads();    // protect LDS reuse across g iterations
        if (tid < 64) {
            int j = g * 64 + tid;
            tokid[tid] = list[j < nrep ? j : nrep - 1];
        }
        __syncthreads();

        float lacc[4] = {0.f, 0.f, 0.f, 0.f};

        for (int nc = 0; nc < DH / 64; ++nc) {
            const int nb = nc * 64;
            float acc[4][4];
            #pragma unroll
            for (int i = 0; i < 4; ++i)
                #pragma unroll
                for (int j = 0; j < 4; ++j) acc[i][j] = 0.f;

            for (int kc = 0; kc < DM / 64; ++kc) {
                const int kb = kc * 64;
                __syncthreads();
                #pragma unroll
                for (int r = 0; r < 4; ++r) {
                    int row = ty + r * 16;
                    *(float4*)(&xsh[row][tx * 4]) =
                        *(const float4*)(x + (size_t)tokid[row] * DM + kb + tx * 4);
                    *(float4*)(&wsd[row][tx * 4]) =
                        *(const float4*)(W1 + (size_t)(kb + row) * DH + nb + tx * 4);
                }
                __syncthreads();
                #pragma unroll
                for (int k4 = 0; k4 < 16; ++k4) {
                    float4 xv[4], wv[4];
                    #pragma unroll
                    for (int q = 0; q < 4; ++q)
                        xv[q] = *(const float4*)(&xsh[ty * 4 + q][k4 * 4]);
                    #pragma unroll
                    for (int q = 0; q < 4; ++q)
                        wv[q] = *(const float4*)(&wsd[k4 * 4 + q][tx * 4]);
                    #pragma unroll
                    for (int mi = 0; mi < 4; ++mi) {
                        const float* xp = (const float*)(&xv[mi]);
                        #pragma unroll
                        for (int kk = 0; kk < 4; ++kk) {
                            const float a = xp[kk];
                            acc[mi][0] = fmaf(a, wv[kk].x, acc[mi][0]);
                            acc[mi][1] = fmaf(a, wv[kk].y, acc[mi][1]);
                            acc[mi][2] = fmaf(a, wv[kk].z, acc[mi][2]);
                            acc[mi][3] = fmaf(a, wv[kk].w, acc[mi][3]);
                        }
                    }
                }
            }

            const float4 b1v = *(const float4*)(b1 + nb + tx * 4);
            #pragma unroll
            for (int mi = 0; mi < 4; ++mi) {
                float4 h;
                h.x = fmaxf(acc[mi][0] + b1v.x, 0.f);
                h.y = fmaxf(acc[mi][1] + b1v.y, 0.f);
                h.z = fmaxf(acc[mi][2] + b1v.z, 0.f);
                h.w = fmaxf(acc[mi][3] + b1v.w, 0.f);
                *(float4*)(&hsh[ty * 4 + mi][tx * 4]) = h;
            }
            {
                const float4 v = *(const float4*)(W2 + (size_t)nb * NE + tid * 4);
                *(float4*)(&w2s[tid * 4]) = v;
            }
            __syncthreads();
            #pragma unroll
            for (int j = 0; j < 4; ++j) {
                const int t = ty + 16 * j;
                float a = lacc[j];
                #pragma unroll
                for (int nq = 0; nq < 16; ++nq) {
                    const float4 hv = *(const float4*)(&hsh[t][nq * 4]);
                    a = fmaf(hv.x, w2s[(nq * 4 + 0) * NE + tx], a);
                    a = fmaf(hv.y, w2s[(nq * 4 + 1) * NE + tx], a);
                    a = fmaf(hv.z, w2s[(nq * 4 + 2) * NE + tx], a);
                    a = fmaf(hv.w, w2s[(nq * 4 + 3) * NE + tx], a);
                }
                lacc[j] = a;
            }
        }

        #pragma unroll
        for (int j = 0; j < 4; ++j)
            lsg[ty + 16 * j][tx] = lacc[j];
        __syncthreads();

        if (tid < 64) {
            const int t = tid;
            float l[NE]; float mx = -1e30f;
            #pragma unroll
            for (int e = 0; e < NE; ++e) {
                l[e] = lsg[t][e] + b2[e];
                mx = fmaxf(mx, l[e]);
            }
            float pb[NE]; float ssum = 0.f;
            #pragma unroll
            for (int e = 0; e < NE; ++e) { pb[e] = expf(l[e] - mx); ssum += pb[e]; }
            float inv = 1.f / ssum;
            #pragma unroll
            for (int e = 0; e < NE; ++e) pb[e] *= inv;

            int i1 = 0; float p1 = pb[0];
            #pragma unroll
            for (int e = 1; e < NE; ++e) if (pb[e] > p1) { p1 = pb[e]; i1 = e; }
            int i2 = -1; float p2 = -1.f;
            #pragma unroll
            for (int e = 0; e < NE; ++e) if (e != i1 && pb[e] > p2) { p2 = pb[e]; i2 = e; }
            float denom = p1 + p2 + 1e-8f;
            size_t gt = (size_t)tokid[t];
            out[gt * 2 + 0] = p1 / denom;
            out[gt * 2 + 1] = p2 / denom;
            out[OFF_IDX + gt * 2 + 0] = (float)i1;
            out[OFF_IDX + gt * 2 + 1] = (float)i2;
            #pragma unroll
            for (int e = 0; e < NE; ++e) out[OFF_PROB + gt * 16 + e] = pb[e];
        }
    }
}

extern "C" void kernel_launch(void* const* d_in, const int* in_sizes, int n_in,
                              void* d_out, int out_size, void* d_ws, size_t ws_size,
                              hipStream_t stream) {
    const float* x  = (const float*)d_in[0];
    const float* W1 = (const float*)d_in[1];
    const float* b1 = (const float*)d_in[2];
    const float* W2 = (const float*)d_in[3];
    const float* b2 = (const float*)d_in[4];
    float* out = (float*)d_out;

    int* cnt  = (int*)d_ws;
    int* list = (int*)((char*)d_ws + WS_LIST);

    hipMemsetAsync(cnt, 0, sizeof(int), stream);
    hipLaunchKernelGGL(router_mfma, dim3(TOKENS / BM), dim3(512), 0, stream,
                       x, W1, b1, W2, b2, out, cnt, list);
    hipLaunchKernelGGL(repair_gather, dim3(32), dim3(256), 0, stream,
                       x, W1, b1, W2, b2, out, cnt, list);
}

// Round 4
// 898.960 us; speedup vs baseline: 9.2955x; 9.2955x over previous
//
#include <hip/hip_runtime.h>
#include <math.h>
#include <stdint.h>

#define TOKENS 32768
#define DM 2048
#define DH 1024
#define NE 16
#define BM 128
#define BN 512
#define NPASS 2
#define NSTAGE 64          // DM / 32
#define TAU 5e-4f

// output layout (floats): gates[T*2] | indices[T*2] | probs[T*16]
#define OFF_IDX  (TOKENS * 2)
#define OFF_PROB (TOKENS * 4)

// ws layout (bytes): [0] count (int), [1024] list (32768 int)  -> 132 KB total
#define WS_LIST 1024

typedef short  bf16x8 __attribute__((ext_vector_type(8)));
typedef float  f32x16 __attribute__((ext_vector_type(16)));

// truncation split: hi = top-16-bit bf16 of f; lo = top-16-bit bf16 of (f - hi).
// pack two adjacent elements' bf16 into one dword (little-endian order).

// ---------------- fused GEMM1(MFMA bf16-split, on-the-fly W1) + GEMM2 + softmax + top2 + flag ----------------
__global__ __launch_bounds__(512, 2)
void router_mfma(const float* __restrict__ x, const float* __restrict__ W1,
                 const float* __restrict__ b1, const float* __restrict__ W2,
                 const float* __restrict__ b2, float* __restrict__ out,
                 int* __restrict__ cnt, int* __restrict__ list)
{
    __shared__ short xs[BM * 64];        // 16 KB: A tile [128 m][8 slots x 8 shorts], XOR-swizzled
    __shared__ short bs[BN * 64];        // 64 KB: B tile [512 n][8 slots x 8 shorts], XOR-swizzled
    __shared__ float w2t[NE * 128];      // 8 KB
    __shared__ float ls[BM * 17];        // padded logits

    float* h_lds = (float*)bs;           // [128][128], reused
    float* lsred = (float*)bs;           // [2048][4], reused

    const int tid  = threadIdx.x;
    const int wid  = tid >> 6;
    const int lane = tid & 63;
    const int l31  = lane & 31;
    const int lh   = lane >> 5;
    const int sg   = lane & 7;           // row&7 for all frag rows (row ≡ l31 mod 8)
    const int wm   = wid >> 2;           // 0..1
    const int wn   = wid & 3;            // 0..3
    const int m0   = blockIdx.x * BM;

    const int tq  = tid & 31;
    const int egq = (tid >> 5) & 3;
    const int ns  = tid >> 7;

    float lacc[4][4];
    #pragma unroll
    for (int i = 0; i < 4; ++i)
        #pragma unroll
        for (int e = 0; e < 4; ++e) lacc[i][e] = 0.f;

    const int arow = tid >> 2, kq = tid & 3;     // A staging assignment
    const int asig = arow & 7;
    const int nloc = (wid << 6) + lane;          // B staging row 0..511
    const int sgl  = lane & 7;

    for (int p = 0; p < NPASS; ++p) {
        f32x16 acc[2][4];
        #pragma unroll
        for (int mf = 0; mf < 2; ++mf)
            #pragma unroll
            for (int nf = 0; nf < 4; ++nf)
                #pragma unroll
                for (int q = 0; q < 16; ++q) acc[mf][nf][q] = 0.f;

        for (int s = 0; s < NSTAGE; ++s) {
            __syncthreads();   // xs/bs free: previous compute done
            // ---- B stage: W1 [32k x 512n] fp32 -> bf16 hi/lo splits, on the fly ----
            {
                const float* wp = W1 + (size_t)(s * 32) * DH + p * BN + nloc;
                short* rb = bs + nloc * 64;
                #pragma unroll
                for (int h = 0; h < 2; ++h) {
                    float f[16];
                    #pragma unroll
                    for (int j = 0; j < 16; ++j)
                        f[j] = wp[(size_t)(h * 16 + j) * DH];
                    uint32_t hd[8], ld_[8];
                    #pragma unroll
                    for (int q = 0; q < 8; ++q) {
                        uint32_t u0 = __float_as_uint(f[2 * q]);
                        uint32_t u1 = __float_as_uint(f[2 * q + 1]);
                        hd[q] = (u0 >> 16) | (u1 & 0xFFFF0000u);
                        float r0 = f[2 * q]     - __uint_as_float(u0 & 0xFFFF0000u);
                        float r1 = f[2 * q + 1] - __uint_as_float(u1 & 0xFFFF0000u);
                        ld_[q] = (__float_as_uint(r0) >> 16) | (__float_as_uint(r1) & 0xFFFF0000u);
                    }
                    *(int4*)(rb + (((2 * h + 0) ^ sgl) << 3)) =
                        make_int4(hd[0], hd[1], hd[2], hd[3]);
                    *(int4*)(rb + (((2 * h + 1) ^ sgl) << 3)) =
                        make_int4(hd[4], hd[5], hd[6], hd[7]);
                    *(int4*)(rb + (((4 + 2 * h + 0) ^ sgl) << 3)) =
                        make_int4(ld_[0], ld_[1], ld_[2], ld_[3]);
                    *(int4*)(rb + (((4 + 2 * h + 1) ^ sgl) << 3)) =
                        make_int4(ld_[4], ld_[5], ld_[6], ld_[7]);
                }
            }
            // ---- A stage: x fp32 -> bf16 hi/lo splits ----
            {
                const float* xp = x + (size_t)(m0 + arow) * DM + s * 32 + kq * 8;
                float4 v0 = *(const float4*)xp;
                float4 v1 = *(const float4*)(xp + 4);
                float f[8] = {v0.x, v0.y, v0.z, v0.w, v1.x, v1.y, v1.z, v1.w};
                uint32_t hd[4], ld_[4];
                #pragma unroll
                for (int q = 0; q < 4; ++q) {
                    uint32_t u0 = __float_as_uint(f[2 * q]);
                    uint32_t u1 = __float_as_uint(f[2 * q + 1]);
                    hd[q] = (u0 >> 16) | (u1 & 0xFFFF0000u);
                    float r0 = f[2 * q]     - __uint_as_float(u0 & 0xFFFF0000u);
                    float r1 = f[2 * q + 1] - __uint_as_float(u1 & 0xFFFF0000u);
                    ld_[q] = (__float_as_uint(r0) >> 16) | (__float_as_uint(r1) & 0xFFFF0000u);
                }
                short* ra = xs + arow * 64;
                *(int4*)(ra + ((kq ^ asig) << 3))       = make_int4(hd[0], hd[1], hd[2], hd[3]);
                *(int4*)(ra + (((4 + kq) ^ asig) << 3)) = make_int4(ld_[0], ld_[1], ld_[2], ld_[3]);
            }
            __syncthreads();
            // ---- compute: 2 ksteps x {x0w0, x0w1, x1w0} ----
            #pragma unroll
            for (int ks = 0; ks < 2; ++ks) {
                bf16x8 a0[2], a1[2], b0[4], b1f[4];
                #pragma unroll
                for (int mf = 0; mf < 2; ++mf) {
                    int base = (wm * 64 + mf * 32 + l31) * 64;
                    a0[mf] = *(const bf16x8*)(xs + base + (((ks * 2 + lh)) ^ sg) * 8);
                    a1[mf] = *(const bf16x8*)(xs + base + (((4 + ks * 2 + lh)) ^ sg) * 8);
                }
                #pragma unroll
                for (int nf = 0; nf < 4; ++nf) {
                    int base = (wn * 128 + nf * 32 + l31) * 64;
                    b0[nf]  = *(const bf16x8*)(bs + base + (((ks * 2 + lh)) ^ sg) * 8);
                    b1f[nf] = *(const bf16x8*)(bs + base + (((4 + ks * 2 + lh)) ^ sg) * 8);
                }
                #pragma unroll
                for (int mf = 0; mf < 2; ++mf)
                    #pragma unroll
                    for (int nf = 0; nf < 4; ++nf) {
                        acc[mf][nf] = __builtin_amdgcn_mfma_f32_32x32x16_bf16(a0[mf], b0[nf],  acc[mf][nf], 0, 0, 0);
                        acc[mf][nf] = __builtin_amdgcn_mfma_f32_32x32x16_bf16(a0[mf], b1f[nf], acc[mf][nf], 0, 0, 0);
                        acc[mf][nf] = __builtin_amdgcn_mfma_f32_32x32x16_bf16(a1[mf], b0[nf],  acc[mf][nf], 0, 0, 0);
                    }
            }
        }

        // ---- pass epilogue: bias+relu -> h chunks, fused GEMM2 (VALU, exact fp32) ----
        for (int ch = 0; ch < 4; ++ch) {
            __syncthreads();
            if (wn == ch) {
                #pragma unroll
                for (int nf = 0; nf < 4; ++nf) {
                    int col = nf * 32 + l31;
                    float bb = b1[p * BN + ch * 128 + col];
                    #pragma unroll
                    for (int mf = 0; mf < 2; ++mf)
                        #pragma unroll
                        for (int r = 0; r < 16; ++r) {
                            int row = wm * 64 + mf * 32 + (r & 3) + 8 * (r >> 2) + 4 * lh;
                            h_lds[row * 128 + col] = fmaxf(acc[mf][nf][r] + bb, 0.f);
                        }
                }
            }
            #pragma unroll
            for (int q = 0; q < 4; ++q) {
                int i = tid * 4 + q;                        // 0..2047
                int nn = i >> 4, e = i & 15;
                w2t[e * 128 + nn] = W2[(size_t)(p * BN + ch * 128 + nn) * NE + e];
            }
            __syncthreads();
            for (int nn = 0; nn < 32; ++nn) {
                int nL = ns * 32 + ((nn + tq) & 31);        // staggered: conflict-free
                float hv[4], wv[4];
                #pragma unroll
                for (int i = 0; i < 4; ++i) hv[i] = h_lds[(tq * 4 + i) * 128 + nL];
                #pragma unroll
                for (int e = 0; e < 4; ++e) wv[e] = w2t[(egq * 4 + e) * 128 + nL];
                #pragma unroll
                for (int i = 0; i < 4; ++i)
                    #pragma unroll
                    for (int e = 0; e < 4; ++e)
                        lacc[i][e] = fmaf(hv[i], wv[e], lacc[i][e]);
            }
        }
    }

    // ---- reduce partial logits over ns slices ----
    __syncthreads();
    #pragma unroll
    for (int i = 0; i < 4; ++i)
        #pragma unroll
        for (int e = 0; e < 4; ++e)
            lsred[((tq * 4 + i) * 16 + egq * 4 + e) * 4 + ns] = lacc[i][e];
    __syncthreads();
    #pragma unroll
    for (int q = 0; q < 4; ++q) {
        int idx = tid * 4 + q;                              // 0..2047
        int t = idx >> 4, e = idx & 15;
        ls[t * 17 + e] = lsred[idx * 4 + 0] + lsred[idx * 4 + 1] +
                         lsred[idx * 4 + 2] + lsred[idx * 4 + 3] + b2[e];
    }
    __syncthreads();

    // ---- softmax + top2 + flag ----
    if (tid < BM) {
        int t = tid;
        float l[NE]; float mx = -1e30f;
        #pragma unroll
        for (int e = 0; e < NE; ++e) { l[e] = ls[t * 17 + e]; mx = fmaxf(mx, l[e]); }
        float pb[NE]; float ssum = 0.f;
        #pragma unroll
        for (int e = 0; e < NE; ++e) { pb[e] = expf(l[e] - mx); ssum += pb[e]; }
        float inv = 1.f / ssum;
        #pragma unroll
        for (int e = 0; e < NE; ++e) pb[e] *= inv;

        int i1 = 0; float p1 = pb[0];
        #pragma unroll
        for (int e = 1; e < NE; ++e) if (pb[e] > p1) { p1 = pb[e]; i1 = e; }
        int i2 = -1; float p2 = -1.f;
        #pragma unroll
        for (int e = 0; e < NE; ++e) if (e != i1 && pb[e] > p2) { p2 = pb[e]; i2 = e; }
        float p3 = -1.f;
        #pragma unroll
        for (int e = 0; e < NE; ++e) if (e != i1 && e != i2 && pb[e] > p3) p3 = pb[e];

        float denom = p1 + p2 + 1e-8f;
        size_t gt = (size_t)(m0 + t);
        out[gt * 2 + 0] = p1 / denom;
        out[gt * 2 + 1] = p2 / denom;
        out[OFF_IDX + gt * 2 + 0] = (float)i1;
        out[OFF_IDX + gt * 2 + 1] = (float)i2;
        #pragma unroll
        for (int e = 0; e < NE; ++e) out[OFF_PROB + gt * 16 + e] = pb[e];

        if (p1 - p2 < TAU || p2 - p3 < TAU) {
            int k = atomicAdd(cnt, 1);
            list[k] = m0 + t;
        }
    }
}

// ---------------- exact fp32 repair: 4 tokens/block streaming GEMM ----------------
__global__ __launch_bounds__(256, 3)
void repair4(const float* __restrict__ x, const float* __restrict__ W1,
             const float* __restrict__ b1, const float* __restrict__ W2,
             const float* __restrict__ b2, float* __restrict__ out,
             const int* __restrict__ cnt, const int* __restrict__ list)
{
    __shared__ float xsh[4][DM];       // 32 KB
    __shared__ float hsh[4][DH];       // 16 KB
    __shared__ float red[256];
    __shared__ float lg[4][NE];
    __shared__ int   tokid[4];

    const int tid  = threadIdx.x;
    const int nrep = cnt[0];

    for (int g = blockIdx.x; g * 4 < nrep; g += gridDim.x) {
        __syncthreads();               // previous iteration fully done
        if (tid < 4) {
            int j = g * 4 + tid;
            tokid[tid] = list[j < nrep ? j : 0];
        }
        __syncthreads();

        // ---- stage 4 x rows (coalesced float4) ----
        #pragma unroll
        for (int i = 0; i < 8; ++i) {
            int slot = tid + i * 256;              // 0..2047 float4 slots
            int t = slot >> 9, c = slot & 511;
            *(float4*)(&xsh[t][c * 4]) =
                *(const float4*)(x + (size_t)tokid[t] * DM + c * 4);
        }
        __syncthreads();

        // ---- GEMM1: thread owns 4 n-cols (tid*4..+3) for all 4 tokens ----
        float acc[4][4];
        #pragma unroll
        for (int t = 0; t < 4; ++t)
            #pragma unroll
            for (int q = 0; q < 4; ++q) acc[t][q] = 0.f;

        for (int k4 = 0; k4 < DM / 4; ++k4) {
            float4 xv[4];
            #pragma unroll
            for (int t = 0; t < 4; ++t)
                xv[t] = *(const float4*)(&xsh[t][k4 * 4]);
            #pragma unroll
            for (int kk = 0; kk < 4; ++kk) {
                const float4 w = *(const float4*)(W1 + (size_t)(k4 * 4 + kk) * DH + tid * 4);
                #pragma unroll
                for (int t = 0; t < 4; ++t) {
                    const float a = ((const float*)&xv[t])[kk];
                    acc[t][0] = fmaf(a, w.x, acc[t][0]);
                    acc[t][1] = fmaf(a, w.y, acc[t][1]);
                    acc[t][2] = fmaf(a, w.z, acc[t][2]);
                    acc[t][3] = fmaf(a, w.w, acc[t][3]);
                }
            }
        }

        // ---- bias + relu -> hsh ----
        {
            const float4 bv = *(const float4*)(b1 + tid * 4);
            #pragma unroll
            for (int t = 0; t < 4; ++t) {
                float4 h;
                h.x = fmaxf(acc[t][0] + bv.x, 0.f);
                h.y = fmaxf(acc[t][1] + bv.y, 0.f);
                h.z = fmaxf(acc[t][2] + bv.z, 0.f);
                h.w = fmaxf(acc[t][3] + bv.w, 0.f);
                *(float4*)(&hsh[t][tid * 4]) = h;
            }
        }
        __syncthreads();

        // ---- GEMM2 partials: tid = sl*64 + t*16 + e ----
        {
            const int e  = tid & 15;
            const int t  = (tid >> 4) & 3;
            const int sl = tid >> 6;
            float ps = 0.f;
            for (int q = 0; q < 256; ++q) {
                int n = sl * 256 + q;
                ps = fmaf(hsh[t][n], W2[n * NE + e], ps);
            }
            red[tid] = ps;
        }
        __syncthreads();
        if (tid < 64) {
            int t = tid >> 4, e = tid & 15;
            lg[t][e] = b2[e] + red[0 * 64 + t * 16 + e] + red[1 * 64 + t * 16 + e]
                             + red[2 * 64 + t * 16 + e] + red[3 * 64 + t * 16 + e];
        }
        __syncthreads();

        // ---- softmax + top2, one thread per valid token ----
        if (tid < 4 && g * 4 + tid < nrep) {
            const int t = tid;
            float l[NE]; float mx = -1e30f;
            #pragma unroll
            for (int e = 0; e < NE; ++e) { l[e] = lg[t][e]; mx = fmaxf(mx, l[e]); }
            float pb[NE]; float ssum = 0.f;
            #pragma unroll
            for (int e = 0; e < NE; ++e) { pb[e] = expf(l[e] - mx); ssum += pb[e]; }
            float inv = 1.f / ssum;
            #pragma unroll
            for (int e = 0; e < NE; ++e) pb[e] *= inv;

            int i1 = 0; float p1 = pb[0];
            #pragma unroll
            for (int e = 1; e < NE; ++e) if (pb[e] > p1) { p1 = pb[e]; i1 = e; }
            int i2 = -1; float p2 = -1.f;
            #pragma unroll
            for (int e = 0; e < NE; ++e) if (e != i1 && pb[e] > p2) { p2 = pb[e]; i2 = e; }
            float denom = p1 + p2 + 1e-8f;
            size_t gt = (size_t)tokid[t];
            out[gt * 2 + 0] = p1 / denom;
            out[gt * 2 + 1] = p2 / denom;
            out[OFF_IDX + gt * 2 + 0] = (float)i1;
            out[OFF_IDX + gt * 2 + 1] = (float)i2;
            #pragma unroll
            for (int e = 0; e < NE; ++e) out[OFF_PROB + gt * 16 + e] = pb[e];
        }
    }
}

extern "C" void kernel_launch(void* const* d_in, const int* in_sizes, int n_in,
                              void* d_out, int out_size, void* d_ws, size_t ws_size,
                              hipStream_t stream) {
    const float* x  = (const float*)d_in[0];
    const float* W1 = (const float*)d_in[1];
    const float* b1 = (const float*)d_in[2];
    const float* W2 = (const float*)d_in[3];
    const float* b2 = (const float*)d_in[4];
    float* out = (float*)d_out;

    int* cnt  = (int*)d_ws;
    int* list = (int*)((char*)d_ws + WS_LIST);

    hipMemsetAsync(cnt, 0, sizeof(int), stream);
    hipLaunchKernelGGL(router_mfma, dim3(TOKENS / BM), dim3(512), 0, stream,
                       x, W1, b1, W2, b2, out, cnt, list);
    hipLaunchKernelGGL(repair4, dim3(512), dim3(256), 0, stream,
                       x, W1, b1, W2, b2, out, cnt, list);
}